// Round 3
// baseline (312.195 us; speedup 1.0000x reference)
//
#include <hip/hip_runtime.h>
#include <hip/hip_bf16.h>

typedef __bf16 bf16;
typedef __bf16 bf16x4 __attribute__((ext_vector_type(4)));
typedef __bf16 bf16x8 __attribute__((ext_vector_type(8)));
typedef float  f32x4  __attribute__((ext_vector_type(4)));

#define AS1 __attribute__((address_space(1)))
#define AS3 __attribute__((address_space(3)))

__device__ __forceinline__ void gload_lds16(const bf16* g, bf16* l) {
    __builtin_amdgcn_global_load_lds((const AS1 void*)g, (AS3 void*)l, 16, 0, 0);
}

__device__ __forceinline__ void stage8_f32(const float* s, bf16* l) {
    float4 a = *(const float4*)s;
    float4 b = *(const float4*)(s + 4);
    bf16x8 o;
    o[0] = (bf16)a.x; o[1] = (bf16)a.y; o[2] = (bf16)a.z; o[3] = (bf16)a.w;
    o[4] = (bf16)b.x; o[5] = (bf16)b.y; o[6] = (bf16)b.z; o[7] = (bf16)b.w;
    *(bf16x8*)l = o;
}

// ---------------------------------------------------------------------------
// 128x128 GEMM tile core: acc += A[M,K] @ B[N,K]^T (bf16 MFMA).
// 2-phase double-buffered staging (prefetch next K-tile before compute,
// single vmcnt/lgkm drain + raw s_barrier per K-step).
// ---------------------------------------------------------------------------
template <bool AF32, bool BF32>
__device__ __forceinline__ void gemm_core(
    const void* __restrict__ Av, const void* __restrict__ Bv,
    int m0, int n0, int K, f32x4 (&acc)[4][4],
    int wm, int wn, int r16, int q8)
{
    constexpr int LDA = AF32 ? 40 : 32;
    constexpr int LDB = BF32 ? 40 : 32;
    __shared__ __align__(16) bf16 As[2][128 * LDA];
    __shared__ __align__(16) bf16 Bs[2][128 * LDB];

    const int tid = threadIdx.x;
    const int i0 = tid, i1 = tid + 256;
    const int r0 = i0 >> 2, c0 = (i0 & 3) * 8;
    const int r1 = i1 >> 2, c1 = (i1 & 3) * 8;
    const size_t a0 = (size_t)(m0 + r0) * K + c0, a1 = (size_t)(m0 + r1) * K + c1;
    const size_t b0 = (size_t)(n0 + r0) * K + c0, b1 = (size_t)(n0 + r1) * K + c1;

    auto stage = [&](int buf, int k0) {
        if constexpr (AF32) {
            stage8_f32((const float*)Av + a0 + k0, &As[buf][r0 * LDA + c0]);
            stage8_f32((const float*)Av + a1 + k0, &As[buf][r1 * LDA + c1]);
        } else {
            gload_lds16((const bf16*)Av + a0 + k0, &As[buf][i0 * 8]);
            gload_lds16((const bf16*)Av + a1 + k0, &As[buf][i1 * 8]);
        }
        if constexpr (BF32) {
            stage8_f32((const float*)Bv + b0 + k0, &Bs[buf][r0 * LDB + c0]);
            stage8_f32((const float*)Bv + b1 + k0, &Bs[buf][r1 * LDB + c1]);
        } else {
            gload_lds16((const bf16*)Bv + b0 + k0, &Bs[buf][i0 * 8]);
            gload_lds16((const bf16*)Bv + b1 + k0, &Bs[buf][i1 * 8]);
        }
    };

    // prologue: stage tile 0 into buf 0 (syncthreads drains vmcnt+lgkm)
    stage(0, 0);
    __syncthreads();

    int cur = 0;
    for (int k0 = 0; k0 < K; k0 += 32) {
        // issue next-tile prefetch into the other buffer BEFORE compute;
        // its latency hides under the 8 ds_reads + 16 MFMAs below.
        if (k0 + 32 < K) stage(cur ^ 1, k0 + 32);

        bf16x8 a[4], b[4];
#pragma unroll
        for (int r = 0; r < 4; ++r)
            a[r] = *(const bf16x8*)&As[cur][(wm + r * 16 + r16) * LDA + q8 * 8];
#pragma unroll
        for (int c = 0; c < 4; ++c)
            b[c] = *(const bf16x8*)&Bs[cur][(wn + c * 16 + r16) * LDB + q8 * 8];
#pragma unroll
        for (int r = 0; r < 4; ++r)
#pragma unroll
            for (int c = 0; c < 4; ++c)
                acc[r][c] = __builtin_amdgcn_mfma_f32_16x16x32_bf16(a[r], b[c], acc[r][c], 0, 0, 0);

        // publish buf[cur^1]: prefetch landed (vmcnt) and this wave's reads
        // of buf[cur] drained (lgkm) -> safe to overwrite buf[cur] next iter.
        asm volatile("s_waitcnt vmcnt(0) lgkmcnt(0)" ::: "memory");
        __builtin_amdgcn_s_barrier();
        __builtin_amdgcn_sched_barrier(0);
        cur ^= 1;
    }
}

// fp32 -> bf16 bulk convert: y selects {x, Wq, Wlk, Wlv, Wo}.
__global__ __launch_bounds__(256) void cvt5(
    const float* __restrict__ s0, const float* __restrict__ s1,
    const float* __restrict__ s2, const float* __restrict__ s3,
    const float* __restrict__ s4,
    bf16* __restrict__ d0, bf16* __restrict__ d1, bf16* __restrict__ d2,
    bf16* __restrict__ d3, bf16* __restrict__ d4)
{
    const float* S[5] = {s0, s1, s2, s3, s4};
    bf16*        D[5] = {d0, d1, d2, d3, d4};
    const int    N[5] = {4194304, 4194304, 1048576, 1048576, 4194304};
    int y = blockIdx.y;
    int base = (blockIdx.x * 256 + threadIdx.x) * 8;
    if (base >= N[y]) return;
    stage8_f32(S[y] + base, D[y] + base);
}

// ---------------------------------------------------------------------------
// Projections: grid=(24,16); bx<16 -> Q (PRE-SCALED by 1/sqrt(128)*log2e so
// attn can use exp2 directly), 16..19 -> LK, 20..23 -> LV stored TRANSPOSED
// as LVt[hd=512][T=2048] (b64-packed epilogue).
// ---------------------------------------------------------------------------
template <bool F32>
__global__ __launch_bounds__(256) void proj_kernel_t(
    const void* __restrict__ x, const void* __restrict__ Wq,
    const void* __restrict__ Wlk, const void* __restrict__ Wlv,
    bf16* __restrict__ Q, bf16* __restrict__ LK, bf16* __restrict__ LVt)
{
    const int bx = blockIdx.x, by = blockIdx.y;
    const int tid = threadIdx.x, lane = tid & 63, wave = tid >> 6;
    const int wm = (wave >> 1) * 64, wn = (wave & 1) * 64;
    const int r16 = lane & 15, q8 = lane >> 4;
    f32x4 acc[4][4] = {};

    const void* Bv; int n0;
    if (bx < 16)      { Bv = Wq;  n0 = bx * 128; }
    else if (bx < 20) { Bv = Wlk; n0 = (bx - 16) * 128; }
    else              { Bv = Wlv; n0 = (bx - 20) * 128; }

    gemm_core<F32, F32>(x, Bv, by * 128, n0, 2048, acc, wm, wn, r16, q8);

    if (bx < 20) {
        bf16* C  = (bx < 16) ? Q : LK;
        int ldc  = (bx < 16) ? 2048 : 512;
        // fold softmax scale*log2e into Q (Q only feeds attn; O invariant)
        const float sc = (bx < 16) ? 0.08838834764831845f * 1.4426950408889634f : 1.0f;
#pragma unroll
        for (int r = 0; r < 4; ++r)
#pragma unroll
            for (int c = 0; c < 4; ++c)
#pragma unroll
                for (int i = 0; i < 4; ++i) {
                    int row = by * 128 + wm + r * 16 + q8 * 4 + i;
                    int col = n0 + wn + c * 16 + r16;
                    C[(size_t)row * ldc + col] = (bf16)(acc[r][c][i] * sc);
                }
    } else {
#pragma unroll
        for (int r = 0; r < 4; ++r)
#pragma unroll
            for (int c = 0; c < 4; ++c) {
                int hd = n0 + wn + c * 16 + r16;
                int tb = by * 128 + wm + r * 16 + q8 * 4;
                bf16x4 pk;
#pragma unroll
                for (int i = 0; i < 4; ++i) pk[i] = (bf16)acc[r][c][i];
                *(bf16x4*)&LVt[(size_t)hd * 2048 + tb] = pk;
            }
    }
}

// Output GEMM: out = ATT(bf16) @ Wo^T -> fp32 d_out. grid=(16,16).
template <bool BF32>
__global__ __launch_bounds__(256) void out_kernel_t(
    const bf16* __restrict__ A, const void* __restrict__ Wo, float* __restrict__ C)
{
    const int tid = threadIdx.x, lane = tid & 63, wave = tid >> 6;
    const int wm = (wave >> 1) * 64, wn = (wave & 1) * 64;
    const int r16 = lane & 15, q8 = lane >> 4;
    f32x4 acc[4][4] = {};
    gemm_core<false, BF32>(A, Wo, blockIdx.y * 128, blockIdx.x * 128, 2048, acc, wm, wn, r16, q8);
#pragma unroll
    for (int r = 0; r < 4; ++r)
#pragma unroll
        for (int c = 0; c < 4; ++c)
#pragma unroll
            for (int i = 0; i < 4; ++i) {
                int row = blockIdx.y * 128 + wm + r * 16 + q8 * 4 + i;
                int col = blockIdx.x * 128 + wn + c * 16 + r16;
                C[(size_t)row * 2048 + col] = acc[r][c][i];
            }
}

// ---------------------------------------------------------------------------
// Attention v5 (LDS-traffic cut; attn4 was LDS-pipe-bound: 416B/thread/iter,
// MfmaUtil 12%):
//  - t-block 256 (4 strips/wave): K/V frag + staging traffic amortized 2x
//  - kb/vb fragment reads hoisted out of the strip loop (were read per-strip)
//  - per-strip private Ps regions: no WAR serialization between strips
//  - Q pre-scaled at proj: exp2f(s) directly, no per-element mul
// grid=(8,64): x = 256-row t block, y = h*4+g. S^T = K*Q^T.
// ---------------------------------------------------------------------------
__global__ __launch_bounds__(256) void attn5(
    const bf16* __restrict__ Q, const bf16* __restrict__ LK,
    const bf16* __restrict__ LVt, bf16* __restrict__ O)
{
    __shared__ __align__(16) bf16 Ks[2][64 * 32];   // [s][d], chunk q^((row>>1)&3)
    __shared__ __align__(16) bf16 Vs[2][32 * 64];   // [d][s], chunk q^(row&7)
    __shared__ __align__(16) bf16 Ps[256 * 72];     // [strip][t][s], LD=72

    const int tid  = threadIdx.x;
    const int lane = tid & 63;
    const int w    = tid >> 6;
    const int r16  = lane & 15;
    const int q8   = lane >> 4;
    const int hg = blockIdx.y, h = hg >> 2, g = hg & 3;
    const int t0 = blockIdx.x * 256;

    // loop-invariant Q B-fragments, one per 16-row strip: B[n=t][k=d]
    bf16x8 qb[4];
#pragma unroll
    for (int p = 0; p < 4; ++p)
        qb[p] = *(const bf16x8*)(Q + (size_t)(t0 + w * 64 + p * 16 + r16) * 2048
                                 + h * 128 + g * 32 + q8 * 8);

    // K staging: thread -> local row kr=tid>>2, swizzled global chunk
    const int kr = tid >> 2;
    const int kq = (tid & 3) ^ ((tid >> 3) & 3);
    const bf16* kg = LK + (size_t)kr * 512 + h * 32 + kq * 8;
    // V staging: local row vd=tid>>3, swizzled global chunk (row 128B coalesced)
    const int vd = tid >> 3;
    const int vq = (tid & 7) ^ ((tid >> 3) & 7);
    const bf16* vg = LVt + (size_t)(h * 32 + vd) * 2048 + vq * 8;

    const int ksw = (r16 >> 1) & 3;   // K read swizzle
    const int vsw = r16 & 7;          // V read swizzle

    f32x4 o_acc[4][2] = {};
    float lsum[4] = {0.f, 0.f, 0.f, 0.f};
    const f32x4 z = {0.f, 0.f, 0.f, 0.f};

    // prologue: stage tile 0 into buf 0 (syncthreads drains vmcnt)
    gload_lds16(kg, &Ks[0][tid * 8]);
    gload_lds16(vg, &Vs[0][tid * 8]);
    __syncthreads();

    int cur = 0;
    for (int sb = 0; sb < 2048; sb += 64) {
        // issue next-tile prefetch into the other buffer BEFORE compute;
        // its latency hides under 32 MFMAs + softmax below.
        if (sb + 64 < 2048) {
            gload_lds16(kg + (size_t)(sb + 64) * 512, &Ks[cur ^ 1][tid * 8]);
            gload_lds16(vg + (sb + 64),               &Vs[cur ^ 1][tid * 8]);
        }
        const bf16* ks = Ks[cur];
        const bf16* vs = Vs[cur];

        // strip-invariant K/V fragments: read ONCE per staged tile
        bf16x8 kb[4], vb[2][2];
#pragma unroll
        for (int c = 0; c < 4; ++c)
            kb[c] = *(const bf16x8*)&ks[(c * 16 + r16) * 32 + (q8 ^ ksw) * 8];
#pragma unroll
        for (int kk = 0; kk < 2; ++kk)
#pragma unroll
            for (int ct = 0; ct < 2; ++ct)
                vb[kk][ct] = *(const bf16x8*)&vs[(ct * 16 + r16) * 64
                                                 + (((kk * 4 + q8) ^ vsw) * 8)];

#pragma unroll
        for (int p = 0; p < 4; ++p) {
            // S^T tile: A = K rows (m=s), B = Q strip p (n=t)
            f32x4 s[4];
            __builtin_amdgcn_s_setprio(1);
#pragma unroll
            for (int c = 0; c < 4; ++c)
                s[c] = __builtin_amdgcn_mfma_f32_16x16x32_bf16(kb[c], qb[p], z, 0, 0, 0);
            __builtin_amdgcn_s_setprio(0);
            // lane holds S[t=w*64+p*16+r16][s=c*16+q8*4+i] -> exp2 -> packed b64
            // (scale pre-folded into Q at proj)
#pragma unroll
            for (int c = 0; c < 4; ++c) {
                bf16x4 pk;
#pragma unroll
                for (int i = 0; i < 4; ++i) {
                    float pv = exp2f(s[c][i]);
                    lsum[p] += pv;
                    pk[i] = (bf16)pv;
                }
                *(bf16x4*)&Ps[(size_t)(p * 64 + w * 16 + r16) * 72 + c * 16 + q8 * 4] = pk;
            }
            // O += P @ V^T : A = P (strip-private region), B = V rows (n=d)
            __builtin_amdgcn_s_setprio(1);
#pragma unroll
            for (int kk = 0; kk < 2; ++kk) {
                bf16x8 ap = *(const bf16x8*)&Ps[(size_t)(p * 64 + w * 16 + r16) * 72
                                                + kk * 32 + q8 * 8];
#pragma unroll
                for (int ct = 0; ct < 2; ++ct)
                    o_acc[p][ct] = __builtin_amdgcn_mfma_f32_16x16x32_bf16(ap, vb[kk][ct], o_acc[p][ct], 0, 0, 0);
            }
            __builtin_amdgcn_s_setprio(0);
        }

        // publish buf[cur^1]: prefetch landed (vmcnt) and this wave's reads of
        // buf[cur] are drained (lgkm) -> safe to overwrite buf[cur] next iter.
        asm volatile("s_waitcnt vmcnt(0) lgkmcnt(0)" ::: "memory");
        __builtin_amdgcn_s_barrier();
        __builtin_amdgcn_sched_barrier(0);
        cur ^= 1;
    }

    // per strip: row-sum for t = w*64+p*16+r16 (reduce over q8 groups), then
    // redistribute to C-layout rows t_local = q8*4+i
#pragma unroll
    for (int p = 0; p < 4; ++p) {
        float l = lsum[p];
        l += __shfl_xor(l, 16);
        l += __shfl_xor(l, 32);
        float ls[4];
#pragma unroll
        for (int i = 0; i < 4; ++i) ls[i] = __shfl(l, q8 * 4 + i);
#pragma unroll
        for (int ct = 0; ct < 2; ++ct)
#pragma unroll
            for (int i = 0; i < 4; ++i) {
                float o = o_acc[p][ct][i] / ls[i];
                int t = t0 + w * 64 + p * 16 + q8 * 4 + i;
                int d = ct * 16 + r16;
                O[(size_t)t * 2048 + h * 128 + g * 32 + d] = (bf16)o;
            }
    }
}

// ---------------------------------------------------------------------------
// Contract (verified R6 bench): inputs fp32, output fp32.
// ---------------------------------------------------------------------------
extern "C" void kernel_launch(void* const* d_in, const int* in_sizes, int n_in,
                              void* d_out, int out_size, void* d_ws, size_t ws_size,
                              hipStream_t stream) {
    const float* x   = (const float*)d_in[0];
    const float* Wq  = (const float*)d_in[1];
    // d_in[2]=Wk, d_in[3]=Wv: computed-but-unused in the reference -> skipped
    const float* Wlk = (const float*)d_in[4];
    const float* Wlv = (const float*)d_in[5];
    const float* Wo  = (const float*)d_in[6];
    float* out = (float*)d_out;

    const size_t M4 = 4194304, M1 = 1048576;
    const size_t need_fast = (M1 + M1 + M4 + M4 + M1 + M1) * 2;  // 24 MB

    if (ws_size >= need_fast) {
        bf16* xb   = (bf16*)d_out;      // d_out scratch: dead before out_kernel writes
        bf16* Wqb  = xb + M4;
        bf16* p    = (bf16*)d_ws;
        bf16* Wlkb = p; p += M1;
        bf16* Wlvb = p; p += M1;
        bf16* Wob  = p; p += M4;
        bf16* Qp   = p; p += M4;
        bf16* LKp  = p; p += M1;
        bf16* LVt  = p;
        bf16* ATT  = Qp;                // alias: attn block reads its own Q cells first

        cvt5<<<dim3(2048, 5), 256, 0, stream>>>(x, Wq, Wlk, Wlv, Wo,
                                                xb, Wqb, Wlkb, Wlvb, Wob);
        proj_kernel_t<false><<<dim3(24, 16), 256, 0, stream>>>(xb, Wqb, Wlkb, Wlvb,
                                                               Qp, LKp, LVt);
        attn5<<<dim3(8, 64), 256, 0, stream>>>(Qp, LKp, LVt, ATT);
        out_kernel_t<false><<<dim3(16, 16), 256, 0, stream>>>(ATT, Wob, out);
    } else {
        bf16* Qp  = (bf16*)d_ws;
        bf16* LKp = Qp + M4;
        bf16* LVt = LKp + M1;
        bf16* ATT = Qp;

        proj_kernel_t<true><<<dim3(24, 16), 256, 0, stream>>>(x, Wq, Wlk, Wlv,
                                                              Qp, LKp, LVt);
        attn5<<<dim3(8, 64), 256, 0, stream>>>(Qp, LKp, LVt, ATT);
        out_kernel_t<true><<<dim3(16, 16), 256, 0, stream>>>(ATT, Wo, out);
    }
}

// Round 7
// 284.630 us; speedup vs baseline: 1.0968x; 1.0968x over previous
//
#include <hip/hip_runtime.h>
#include <hip/hip_bf16.h>

typedef __bf16 bf16;
typedef __bf16 bf16x4 __attribute__((ext_vector_type(4)));
typedef __bf16 bf16x8 __attribute__((ext_vector_type(8)));
typedef float  f32x4  __attribute__((ext_vector_type(4)));

#define AS1 __attribute__((address_space(1)))
#define AS3 __attribute__((address_space(3)))

__device__ __forceinline__ void gload_lds16(const bf16* g, bf16* l) {
    __builtin_amdgcn_global_load_lds((const AS1 void*)g, (AS3 void*)l, 16, 0, 0);
}

__device__ __forceinline__ void stage8_f32(const float* s, bf16* l) {
    float4 a = *(const float4*)s;
    float4 b = *(const float4*)(s + 4);
    bf16x8 o;
    o[0] = (bf16)a.x; o[1] = (bf16)a.y; o[2] = (bf16)a.z; o[3] = (bf16)a.w;
    o[4] = (bf16)b.x; o[5] = (bf16)b.y; o[6] = (bf16)b.z; o[7] = (bf16)b.w;
    *(bf16x8*)l = o;
}

// ---------------------------------------------------------------------------
// 128x64 GEMM tile core: acc += A[128,K] @ B[64,K]^T (bf16 MFMA).
// Reshaped from the verified 128x128 core. 4 waves, each 32 rows x 64 cols
// (wm = wave*32, acc[2][4]). 2-phase double-buffered staging. Rationale:
// both GEMMs are GRID-limited (out: 256 blocks = 1 block/CU; proj: 1.5/CU
// + 128-block tail). 64-wide tiles double the grid -> 2-3 blocks/CU uniform.
// ---------------------------------------------------------------------------
template <bool AF32, bool BF32>
__device__ __forceinline__ void gemm_core64(
    const void* __restrict__ Av, const void* __restrict__ Bv,
    int m0, int n0, int K, f32x4 (&acc)[2][4],
    int wm, int r16, int q8)
{
    constexpr int LDA = AF32 ? 40 : 32;
    constexpr int LDB = BF32 ? 40 : 32;
    __shared__ __align__(16) bf16 As[2][128 * LDA];
    __shared__ __align__(16) bf16 Bs[2][64 * LDB];

    const int tid = threadIdx.x;
    const int i0 = tid, i1 = tid + 256;
    const int rA0 = i0 >> 2, rA1 = i1 >> 2;      // 0..63, 64..127
    const int rB  = tid >> 2;                    // 0..63
    const int c0  = (tid & 3) * 8;
    const size_t a0 = (size_t)(m0 + rA0) * K + c0;
    const size_t a1 = (size_t)(m0 + rA1) * K + c0;
    const size_t b0 = (size_t)(n0 + rB)  * K + c0;

    auto stage = [&](int buf, int k0) {
        if constexpr (AF32) {
            stage8_f32((const float*)Av + a0 + k0, &As[buf][rA0 * LDA + c0]);
            stage8_f32((const float*)Av + a1 + k0, &As[buf][rA1 * LDA + c0]);
        } else {
            gload_lds16((const bf16*)Av + a0 + k0, &As[buf][i0 * 8]);
            gload_lds16((const bf16*)Av + a1 + k0, &As[buf][i1 * 8]);
        }
        if constexpr (BF32) {
            stage8_f32((const float*)Bv + b0 + k0, &Bs[buf][rB * LDB + c0]);
        } else {
            gload_lds16((const bf16*)Bv + b0 + k0, &Bs[buf][tid * 8]);
        }
    };

    stage(0, 0);
    __syncthreads();

    int cur = 0;
    for (int k0 = 0; k0 < K; k0 += 32) {
        if (k0 + 32 < K) stage(cur ^ 1, k0 + 32);

        bf16x8 a[2], b[4];
#pragma unroll
        for (int r = 0; r < 2; ++r)
            a[r] = *(const bf16x8*)&As[cur][(wm + r * 16 + r16) * LDA + q8 * 8];
#pragma unroll
        for (int c = 0; c < 4; ++c)
            b[c] = *(const bf16x8*)&Bs[cur][(c * 16 + r16) * LDB + q8 * 8];
#pragma unroll
        for (int r = 0; r < 2; ++r)
#pragma unroll
            for (int c = 0; c < 4; ++c)
                acc[r][c] = __builtin_amdgcn_mfma_f32_16x16x32_bf16(a[r], b[c], acc[r][c], 0, 0, 0);

        // publish buf[cur^1]: prefetch landed (vmcnt) and this wave's reads
        // of buf[cur] drained (lgkm) -> safe to overwrite buf[cur] next iter.
        asm volatile("s_waitcnt vmcnt(0) lgkmcnt(0)" ::: "memory");
        __builtin_amdgcn_s_barrier();
        __builtin_amdgcn_sched_barrier(0);
        cur ^= 1;
    }
}

// fp32 -> bf16 bulk convert: y selects {x, Wq, Wlk, Wlv, Wo}.
__global__ __launch_bounds__(256) void cvt5(
    const float* __restrict__ s0, const float* __restrict__ s1,
    const float* __restrict__ s2, const float* __restrict__ s3,
    const float* __restrict__ s4,
    bf16* __restrict__ d0, bf16* __restrict__ d1, bf16* __restrict__ d2,
    bf16* __restrict__ d3, bf16* __restrict__ d4)
{
    const float* S[5] = {s0, s1, s2, s3, s4};
    bf16*        D[5] = {d0, d1, d2, d3, d4};
    const int    N[5] = {4194304, 4194304, 1048576, 1048576, 4194304};
    int y = blockIdx.y;
    int base = (blockIdx.x * 256 + threadIdx.x) * 8;
    if (base >= N[y]) return;
    stage8_f32(S[y] + base, D[y] + base);
}

// ---------------------------------------------------------------------------
// Projections: grid=(48,16), 64-wide N tiles; bx<32 -> Q (PRE-SCALED by
// 1/sqrt(128)*log2e), 32..39 -> LK, 40..47 -> LV stored TRANSPOSED as
// LVt[hd=512][T=2048]. 768 blocks = 3 blocks/CU uniform (no tail).
// ---------------------------------------------------------------------------
template <bool F32>
__global__ __launch_bounds__(256) void proj_kernel_t(
    const void* __restrict__ x, const void* __restrict__ Wq,
    const void* __restrict__ Wlk, const void* __restrict__ Wlv,
    bf16* __restrict__ Q, bf16* __restrict__ LK, bf16* __restrict__ LVt)
{
    const int bx = blockIdx.x, by = blockIdx.y;
    const int tid = threadIdx.x, lane = tid & 63, wave = tid >> 6;
    const int wm = wave * 32;
    const int r16 = lane & 15, q8 = lane >> 4;
    f32x4 acc[2][4] = {};

    const void* Bv; int n0;
    if (bx < 32)      { Bv = Wq;  n0 = bx * 64; }
    else if (bx < 40) { Bv = Wlk; n0 = (bx - 32) * 64; }
    else              { Bv = Wlv; n0 = (bx - 40) * 64; }

    gemm_core64<F32, F32>(x, Bv, by * 128, n0, 2048, acc, wm, r16, q8);

    if (bx < 40) {
        bf16* C  = (bx < 32) ? Q : LK;
        int ldc  = (bx < 32) ? 2048 : 512;
        const float sc = (bx < 32) ? 0.08838834764831845f * 1.4426950408889634f : 1.0f;
#pragma unroll
        for (int r = 0; r < 2; ++r)
#pragma unroll
            for (int c = 0; c < 4; ++c)
#pragma unroll
                for (int i = 0; i < 4; ++i) {
                    int row = by * 128 + wm + r * 16 + q8 * 4 + i;
                    int col = n0 + c * 16 + r16;
                    C[(size_t)row * ldc + col] = (bf16)(acc[r][c][i] * sc);
                }
    } else {
#pragma unroll
        for (int r = 0; r < 2; ++r)
#pragma unroll
            for (int c = 0; c < 4; ++c) {
                int hd = n0 + c * 16 + r16;
                int tb = by * 128 + wm + r * 16 + q8 * 4;
                bf16x4 pk;
#pragma unroll
                for (int i = 0; i < 4; ++i) pk[i] = (bf16)acc[r][c][i];
                *(bf16x4*)&LVt[(size_t)hd * 2048 + tb] = pk;
            }
    }
}

// Output GEMM: out = ATT(bf16) @ Wo^T -> fp32 d_out. grid=(32,16), 64-wide
// tiles: 512 blocks = 2 blocks/CU (was 1 with 128x128).
template <bool BF32>
__global__ __launch_bounds__(256) void out_kernel_t(
    const bf16* __restrict__ A, const void* __restrict__ Wo, float* __restrict__ C)
{
    const int tid = threadIdx.x, lane = tid & 63, wave = tid >> 6;
    const int wm = wave * 32;
    const int r16 = lane & 15, q8 = lane >> 4;
    f32x4 acc[2][4] = {};
    gemm_core64<false, BF32>(A, Wo, blockIdx.y * 128, blockIdx.x * 64, 2048, acc, wm, r16, q8);
#pragma unroll
    for (int r = 0; r < 2; ++r)
#pragma unroll
        for (int c = 0; c < 4; ++c)
#pragma unroll
            for (int i = 0; i < 4; ++i) {
                int row = blockIdx.y * 128 + wm + r * 16 + q8 * 4 + i;
                int col = blockIdx.x * 64 + c * 16 + r16;
                C[(size_t)row * 2048 + col] = acc[r][c][i];
            }
}

// ---------------------------------------------------------------------------
// Attention v6 (latency-bound fix; v5 showed LDS-traffic was NOT the limit):
//  - t-block 128, grid (16,64)=1024 blocks -> 4 blocks/CU (v5 was grid-limited
//    at 2/CU, 19% occupancy)
//  - phase-split: QK+exp+Pwrite for BOTH strips, then all PV -> strip 1's
//    VALU work covers strip 0's LDS write->read latency
//  - lsum via ones-MFMA on the idle matrix pipe (C row q8*4+i = exactly the
//    epilogue row) -> deletes 64 fadd/iter + the shuffle-reduce epilogue
//  - Ps: LD=64 (stride 32 dwords = 0 mod 32 banks) + 8-elem-group XOR swizzle
//    gr^=(r16&7): b128 reads & b64 writes both uniform/bank (conflict-free)
// ---------------------------------------------------------------------------
__global__ __launch_bounds__(256, 4) void attn6(
    const bf16* __restrict__ Q, const bf16* __restrict__ LK,
    const bf16* __restrict__ LVt, bf16* __restrict__ O)
{
    __shared__ __align__(16) bf16 Ks[2][64 * 32];   // [s][d], chunk q^((row>>1)&3)
    __shared__ __align__(16) bf16 Vs[2][32 * 64];   // [d][s], chunk q^(row&7)
    __shared__ __align__(16) bf16 Ps[128 * 64];     // 8 regions x 16 rows x 64, XOR-swz

    const int tid  = threadIdx.x;
    const int lane = tid & 63;
    const int w    = tid >> 6;
    const int r16  = lane & 15;
    const int q8   = lane >> 4;
    const int hg = blockIdx.y, h = hg >> 2, g = hg & 3;
    const int t0 = blockIdx.x * 128;

    // loop-invariant Q B-fragments, one per 16-row strip: B[n=t][k=d]
    bf16x8 qb[2];
#pragma unroll
    for (int p = 0; p < 2; ++p)
        qb[p] = *(const bf16x8*)(Q + (size_t)(t0 + w * 32 + p * 16 + r16) * 2048
                                 + h * 128 + g * 32 + q8 * 8);

    // K staging: thread -> local row kr=tid>>2, swizzled global chunk
    const int kr = tid >> 2;
    const int kq = (tid & 3) ^ ((tid >> 3) & 3);
    const bf16* kg = LK + (size_t)kr * 512 + h * 32 + kq * 8;
    // V staging: local row vd=tid>>3, swizzled global chunk (row 128B coalesced)
    const int vd = tid >> 3;
    const int vq = (tid & 7) ^ ((tid >> 3) & 7);
    const bf16* vg = LVt + (size_t)(h * 32 + vd) * 2048 + vq * 8;

    const int ksw = (r16 >> 1) & 3;   // K read swizzle
    const int vsw = r16 & 7;          // V read swizzle

    // Ps addressing (all int, conflict-free XOR layout)
    const int pk7 = r16 & 7;          // row XOR key
    const int ph  = q8 >> 1;          // write gr sub-index
    const int plo = (q8 & 1) * 4;     // write half-gr offset (elems)
    const int pb0 = ((w * 2 + 0) * 16 + r16) * 64;
    const int pb1 = ((w * 2 + 1) * 16 + r16) * 64;

    // all-ones B fragment for row-sum MFMA
    bf16x8 ones;
#pragma unroll
    for (int j = 0; j < 8; ++j) ones[j] = (bf16)1.0f;

    f32x4 o_acc[2][2] = {};
    f32x4 l_acc[2] = {};
    const f32x4 z = {0.f, 0.f, 0.f, 0.f};

    // prologue: stage tile 0 into buf 0 (syncthreads drains vmcnt)
    gload_lds16(kg, &Ks[0][tid * 8]);
    gload_lds16(vg, &Vs[0][tid * 8]);
    __syncthreads();

    int cur = 0;
    for (int sb = 0; sb < 2048; sb += 64) {
        if (sb + 64 < 2048) {
            gload_lds16(kg + (size_t)(sb + 64) * 512, &Ks[cur ^ 1][tid * 8]);
            gload_lds16(vg + (sb + 64),               &Vs[cur ^ 1][tid * 8]);
        }
        const bf16* ks = Ks[cur];
        const bf16* vs = Vs[cur];

        // strip-invariant K/V fragments: read ONCE per staged tile
        bf16x8 kb[4], vb[2][2];
#pragma unroll
        for (int c = 0; c < 4; ++c)
            kb[c] = *(const bf16x8*)&ks[(c * 16 + r16) * 32 + (q8 ^ ksw) * 8];
#pragma unroll
        for (int kk = 0; kk < 2; ++kk)
#pragma unroll
            for (int ct = 0; ct < 2; ++ct)
                vb[kk][ct] = *(const bf16x8*)&vs[(ct * 16 + r16) * 64
                                                 + (((kk * 4 + q8) ^ vsw) * 8)];

        // ---- phase A: QK^T + exp + P-write for both strips ----
#pragma unroll
        for (int p = 0; p < 2; ++p) {
            const int pbase = p ? pb1 : pb0;
            f32x4 s[4];
            __builtin_amdgcn_s_setprio(1);
#pragma unroll
            for (int c = 0; c < 4; ++c)
                s[c] = __builtin_amdgcn_mfma_f32_16x16x32_bf16(kb[c], qb[p], z, 0, 0, 0);
            __builtin_amdgcn_s_setprio(0);
            // lane holds S[t=r16][s=c*16+q8*4+i]; scale pre-folded into Q
#pragma unroll
            for (int c = 0; c < 4; ++c) {
                bf16x4 pkv;
#pragma unroll
                for (int i = 0; i < 4; ++i) pkv[i] = (bf16)exp2f(s[c][i]);
                *(bf16x4*)&Ps[pbase + ((c * 2 + ph) ^ pk7) * 8 + plo] = pkv;
            }
        }

        // ---- phase B: PV + row-sum MFMAs for both strips ----
        __builtin_amdgcn_s_setprio(1);
#pragma unroll
        for (int p = 0; p < 2; ++p) {
            const int pbase = p ? pb1 : pb0;
#pragma unroll
            for (int kk = 0; kk < 2; ++kk) {
                bf16x8 ap = *(const bf16x8*)&Ps[pbase + ((kk * 4 + q8) ^ pk7) * 8];
#pragma unroll
                for (int ct = 0; ct < 2; ++ct)
                    o_acc[p][ct] = __builtin_amdgcn_mfma_f32_16x16x32_bf16(ap, vb[kk][ct], o_acc[p][ct], 0, 0, 0);
                l_acc[p] = __builtin_amdgcn_mfma_f32_16x16x32_bf16(ap, ones, l_acc[p], 0, 0, 0);
            }
        }
        __builtin_amdgcn_s_setprio(0);

        // publish buf[cur^1]: prefetch landed (vmcnt) and this wave's reads of
        // buf[cur] drained (lgkm) -> safe to overwrite buf[cur] next iter.
        asm volatile("s_waitcnt vmcnt(0) lgkmcnt(0)" ::: "memory");
        __builtin_amdgcn_s_barrier();
        __builtin_amdgcn_sched_barrier(0);
        cur ^= 1;
    }

    // epilogue: l_acc[p][i] IS the row-sum for t_local = q8*4+i (no shuffles)
#pragma unroll
    for (int p = 0; p < 2; ++p)
#pragma unroll
        for (int i = 0; i < 4; ++i) {
            float inv = 1.0f / l_acc[p][i];
            int t = t0 + w * 32 + p * 16 + q8 * 4 + i;
#pragma unroll
            for (int ct = 0; ct < 2; ++ct) {
                int d = ct * 16 + r16;
                O[(size_t)t * 2048 + h * 128 + g * 32 + d] = (bf16)(o_acc[p][ct][i] * inv);
            }
        }
}

// ---------------------------------------------------------------------------
// Contract (verified R6 bench): inputs fp32, output fp32.
// ---------------------------------------------------------------------------
extern "C" void kernel_launch(void* const* d_in, const int* in_sizes, int n_in,
                              void* d_out, int out_size, void* d_ws, size_t ws_size,
                              hipStream_t stream) {
    const float* x   = (const float*)d_in[0];
    const float* Wq  = (const float*)d_in[1];
    // d_in[2]=Wk, d_in[3]=Wv: computed-but-unused in the reference -> skipped
    const float* Wlk = (const float*)d_in[4];
    const float* Wlv = (const float*)d_in[5];
    const float* Wo  = (const float*)d_in[6];
    float* out = (float*)d_out;

    const size_t M4 = 4194304, M1 = 1048576;
    const size_t need_fast = (M1 + M1 + M4 + M4 + M1 + M1) * 2;  // 24 MB

    if (ws_size >= need_fast) {
        bf16* xb   = (bf16*)d_out;      // d_out scratch: dead before out_kernel writes
        bf16* Wqb  = xb + M4;
        bf16* p    = (bf16*)d_ws;
        bf16* Wlkb = p; p += M1;
        bf16* Wlvb = p; p += M1;
        bf16* Wob  = p; p += M4;
        bf16* Qp   = p; p += M4;
        bf16* LKp  = p; p += M1;
        bf16* LVt  = p;
        bf16* ATT  = Qp;                // alias: attn block reads its own Q cells first

        cvt5<<<dim3(2048, 5), 256, 0, stream>>>(x, Wq, Wlk, Wlv, Wo,
                                                xb, Wqb, Wlkb, Wlvb, Wob);
        proj_kernel_t<false><<<dim3(48, 16), 256, 0, stream>>>(xb, Wqb, Wlkb, Wlvb,
                                                               Qp, LKp, LVt);
        attn6<<<dim3(16, 64), 256, 0, stream>>>(Qp, LKp, LVt, ATT);
        out_kernel_t<false><<<dim3(32, 16), 256, 0, stream>>>(ATT, Wob, out);
    } else {
        bf16* Qp  = (bf16*)d_ws;
        bf16* LKp = Qp + M4;
        bf16* LVt = LKp + M1;
        bf16* ATT = Qp;

        proj_kernel_t<true><<<dim3(48, 16), 256, 0, stream>>>(x, Wq, Wlk, Wlv,
                                                              Qp, LKp, LVt);
        attn6<<<dim3(16, 64), 256, 0, stream>>>(Qp, LKp, LVt, ATT);
        out_kernel_t<true><<<dim3(32, 16), 256, 0, stream>>>(ATT, Wo, out);
    }
}

// Round 8
// 267.033 us; speedup vs baseline: 1.1691x; 1.0659x over previous
//
#include <hip/hip_runtime.h>
#include <hip/hip_bf16.h>

typedef __bf16 bf16;
typedef __bf16 bf16x4 __attribute__((ext_vector_type(4)));
typedef __bf16 bf16x8 __attribute__((ext_vector_type(8)));
typedef float  f32x4  __attribute__((ext_vector_type(4)));

#define AS1 __attribute__((address_space(1)))
#define AS3 __attribute__((address_space(3)))

__device__ __forceinline__ void gload_lds16(const bf16* g, bf16* l) {
    __builtin_amdgcn_global_load_lds((const AS1 void*)g, (AS3 void*)l, 16, 0, 0);
}

__device__ __forceinline__ void stage8_f32(const float* s, bf16* l) {
    float4 a = *(const float4*)s;
    float4 b = *(const float4*)(s + 4);
    bf16x8 o;
    o[0] = (bf16)a.x; o[1] = (bf16)a.y; o[2] = (bf16)a.z; o[3] = (bf16)a.w;
    o[4] = (bf16)b.x; o[5] = (bf16)b.y; o[6] = (bf16)b.z; o[7] = (bf16)b.w;
    *(bf16x8*)l = o;
}

// ---------------------------------------------------------------------------
// 128x64 GEMM tile core, BK=32, fp32-staging fallback (slow path only).
// ---------------------------------------------------------------------------
__device__ __forceinline__ void gemm_core64_f32(
    const float* __restrict__ Av, const float* __restrict__ Bv,
    int m0, int n0, int K, f32x4 (&acc)[2][4],
    int wm, int r16, int q8)
{
    constexpr int LDA = 40;
    constexpr int LDB = 40;
    __shared__ __align__(16) bf16 As[2][128 * LDA];
    __shared__ __align__(16) bf16 Bs[2][64 * LDB];

    const int tid = threadIdx.x;
    const int rA0 = tid >> 2, rA1 = (tid + 256) >> 2;
    const int rB  = tid >> 2;
    const int c0  = (tid & 3) * 8;
    const size_t a0 = (size_t)(m0 + rA0) * K + c0;
    const size_t a1 = (size_t)(m0 + rA1) * K + c0;
    const size_t b0 = (size_t)(n0 + rB)  * K + c0;

    auto stage = [&](int buf, int k0) {
        stage8_f32(Av + a0 + k0, &As[buf][rA0 * LDA + c0]);
        stage8_f32(Av + a1 + k0, &As[buf][rA1 * LDA + c0]);
        stage8_f32(Bv + b0 + k0, &Bs[buf][rB * LDB + c0]);
    };

    stage(0, 0);
    __syncthreads();

    int cur = 0;
    for (int k0 = 0; k0 < K; k0 += 32) {
        if (k0 + 32 < K) stage(cur ^ 1, k0 + 32);

        bf16x8 a[2], b[4];
#pragma unroll
        for (int r = 0; r < 2; ++r)
            a[r] = *(const bf16x8*)&As[cur][(wm + r * 16 + r16) * LDA + q8 * 8];
#pragma unroll
        for (int c = 0; c < 4; ++c)
            b[c] = *(const bf16x8*)&Bs[cur][(c * 16 + r16) * LDB + q8 * 8];
#pragma unroll
        for (int r = 0; r < 2; ++r)
#pragma unroll
            for (int c = 0; c < 4; ++c)
                acc[r][c] = __builtin_amdgcn_mfma_f32_16x16x32_bf16(a[r], b[c], acc[r][c], 0, 0, 0);

        asm volatile("s_waitcnt vmcnt(0) lgkmcnt(0)" ::: "memory");
        __builtin_amdgcn_s_barrier();
        __builtin_amdgcn_sched_barrier(0);
        cur ^= 1;
    }
}

// ---------------------------------------------------------------------------
// 128x64 GEMM tile core, BK=64, bf16 fast path.
// Rationale (R7 counters): with BK=32 each K-step was 8 MFMAs against a full
// vmcnt(0) drain + barrier -> drain-dominated. BK=64 halves barrier count and
// doubles per-phase MFMA density (16 MFMA + 12 ds_read per phase).
// LDS layout: linear [row][64] is a 16-way read conflict (128B row stride),
// so 16B-group XOR swizzle gph = glog ^ (row&7), applied BOTH sides (rule
// #21): linear gload_lds dest + inverse-swizzled GLOBAL src + swizzled read.
// Read bank check: dword off ((kc*4+q8)^(r16&7))*4 -> uniform 8/bank (floor).
// Staging stays coalesced: permutation is within each 128B line.
// ---------------------------------------------------------------------------
__device__ __forceinline__ void gemm_core64_k64(
    const bf16* __restrict__ A, const bf16* __restrict__ B,
    int m0, int n0, int K, f32x4 (&acc)[2][4],
    int wm, int r16, int q8)
{
    __shared__ __align__(16) bf16 As[2][128 * 64];  // 16 KB each
    __shared__ __align__(16) bf16 Bs[2][64 * 64];   //  8 KB each

    const int tid  = threadIdx.x;
    const int arow = tid >> 3;                              // 0..31
    const int acol = ((tid & 7) ^ ((tid >> 3) & 7)) * 8;    // inverse-swz src col
    const int k7   = r16 & 7;                               // read swizzle key

    auto stage = [&](int buf, int kt) {
        // A: 4 rounds of 32 rows; B: 2 rounds. dest linear slot (j*256+tid)*8.
#pragma unroll
        for (int j = 0; j < 4; ++j)
            gload_lds16(A + (size_t)(m0 + j * 32 + arow) * K + kt + acol,
                        &As[buf][(j * 256 + tid) * 8]);
#pragma unroll
        for (int j = 0; j < 2; ++j)
            gload_lds16(B + (size_t)(n0 + j * 32 + arow) * K + kt + acol,
                        &Bs[buf][(j * 256 + tid) * 8]);
    };

    stage(0, 0);
    __syncthreads();

    int cur = 0;
    for (int kt = 0; kt < K; kt += 64) {
        if (kt + 64 < K) stage(cur ^ 1, kt + 64);

        bf16x8 a[2][2], b[4][2];
#pragma unroll
        for (int r = 0; r < 2; ++r)
#pragma unroll
            for (int kc = 0; kc < 2; ++kc)
                a[r][kc] = *(const bf16x8*)&As[cur][(wm + r * 16 + r16) * 64
                                                   + ((kc * 4 + q8) ^ k7) * 8];
#pragma unroll
        for (int c = 0; c < 4; ++c)
#pragma unroll
            for (int kc = 0; kc < 2; ++kc)
                b[c][kc] = *(const bf16x8*)&Bs[cur][(c * 16 + r16) * 64
                                                   + ((kc * 4 + q8) ^ k7) * 8];
#pragma unroll
        for (int kc = 0; kc < 2; ++kc)
#pragma unroll
            for (int r = 0; r < 2; ++r)
#pragma unroll
                for (int c = 0; c < 4; ++c)
                    acc[r][c] = __builtin_amdgcn_mfma_f32_16x16x32_bf16(a[r][kc], b[c][kc], acc[r][c], 0, 0, 0);

        // publish buf[cur^1]: prefetch landed (vmcnt), reads of buf[cur]
        // drained (lgkm) -> safe to overwrite buf[cur] next iter.
        asm volatile("s_waitcnt vmcnt(0) lgkmcnt(0)" ::: "memory");
        __builtin_amdgcn_s_barrier();
        __builtin_amdgcn_sched_barrier(0);
        cur ^= 1;
    }
}

// fp32 -> bf16 bulk convert: y selects {x, Wq, Wlk, Wlv, Wo}.
__global__ __launch_bounds__(256) void cvt5(
    const float* __restrict__ s0, const float* __restrict__ s1,
    const float* __restrict__ s2, const float* __restrict__ s3,
    const float* __restrict__ s4,
    bf16* __restrict__ d0, bf16* __restrict__ d1, bf16* __restrict__ d2,
    bf16* __restrict__ d3, bf16* __restrict__ d4)
{
    const float* S[5] = {s0, s1, s2, s3, s4};
    bf16*        D[5] = {d0, d1, d2, d3, d4};
    const int    N[5] = {4194304, 4194304, 1048576, 1048576, 4194304};
    int y = blockIdx.y;
    int base = (blockIdx.x * 256 + threadIdx.x) * 8;
    if (base >= N[y]) return;
    stage8_f32(S[y] + base, D[y] + base);
}

// ---------------------------------------------------------------------------
// Projections: grid=(48,16), 64-wide N tiles; bx<32 -> Q (PRE-SCALED by
// 1/sqrt(128)*log2e), 32..39 -> LK, 40..47 -> LV stored TRANSPOSED as
// LVt[hd=512][T=2048]. 768 blocks = 3 blocks/CU uniform.
// ---------------------------------------------------------------------------
template <bool F32>
__global__ __launch_bounds__(256) void proj_kernel_t(
    const void* __restrict__ x, const void* __restrict__ Wq,
    const void* __restrict__ Wlk, const void* __restrict__ Wlv,
    bf16* __restrict__ Q, bf16* __restrict__ LK, bf16* __restrict__ LVt)
{
    const int bx = blockIdx.x, by = blockIdx.y;
    const int tid = threadIdx.x, lane = tid & 63, wave = tid >> 6;
    const int wm = wave * 32;
    const int r16 = lane & 15, q8 = lane >> 4;
    f32x4 acc[2][4] = {};

    const void* Bv; int n0;
    if (bx < 32)      { Bv = Wq;  n0 = bx * 64; }
    else if (bx < 40) { Bv = Wlk; n0 = (bx - 32) * 64; }
    else              { Bv = Wlv; n0 = (bx - 40) * 64; }

    if constexpr (F32)
        gemm_core64_f32((const float*)x, (const float*)Bv, by * 128, n0, 2048, acc, wm, r16, q8);
    else
        gemm_core64_k64((const bf16*)x, (const bf16*)Bv, by * 128, n0, 2048, acc, wm, r16, q8);

    if (bx < 40) {
        bf16* C  = (bx < 32) ? Q : LK;
        int ldc  = (bx < 32) ? 2048 : 512;
        const float sc = (bx < 32) ? 0.08838834764831845f * 1.4426950408889634f : 1.0f;
#pragma unroll
        for (int r = 0; r < 2; ++r)
#pragma unroll
            for (int c = 0; c < 4; ++c)
#pragma unroll
                for (int i = 0; i < 4; ++i) {
                    int row = by * 128 + wm + r * 16 + q8 * 4 + i;
                    int col = n0 + c * 16 + r16;
                    C[(size_t)row * ldc + col] = (bf16)(acc[r][c][i] * sc);
                }
    } else {
#pragma unroll
        for (int r = 0; r < 2; ++r)
#pragma unroll
            for (int c = 0; c < 4; ++c) {
                int hd = n0 + c * 16 + r16;
                int tb = by * 128 + wm + r * 16 + q8 * 4;
                bf16x4 pk;
#pragma unroll
                for (int i = 0; i < 4; ++i) pk[i] = (bf16)acc[r][c][i];
                *(bf16x4*)&LVt[(size_t)hd * 2048 + tb] = pk;
            }
    }
}

// Output GEMM: out = ATT(bf16) @ Wo^T -> fp32 d_out. grid=(32,16).
template <bool BF32>
__global__ __launch_bounds__(256) void out_kernel_t(
    const bf16* __restrict__ A, const void* __restrict__ Wo, float* __restrict__ C)
{
    const int tid = threadIdx.x, lane = tid & 63, wave = tid >> 6;
    const int wm = wave * 32;
    const int r16 = lane & 15, q8 = lane >> 4;
    f32x4 acc[2][4] = {};
    if constexpr (BF32) {
        // fallback: A bf16, Wo fp32 -- reuse fp32 core with A restaged via
        // the bf16 path is unavailable here; stage both via f32 core's B path
        // is incorrect for A, so use the k64 core only when both are bf16.
        // Slow path stages Wo as fp32:
        __shared__ int dummy; (void)dummy;
        // A is bf16 in both paths; only Wo dtype differs.
    }
    if constexpr (!BF32)
        gemm_core64_k64(A, (const bf16*)Wo, blockIdx.y * 128, blockIdx.x * 64, 2048, acc, wm, r16, q8);
    else {
        // slow path: convert-on-stage Wo (fp32) with BK=32 core layout.
        // A (bf16) staged via gload; implemented inline for correctness.
        constexpr int LDA = 32, LDB = 40;
        __shared__ __align__(16) bf16 As[2][128 * LDA];
        __shared__ __align__(16) bf16 Bs[2][64 * LDB];
        const int i0 = tid, i1 = tid + 256;
        const int rB = tid >> 2, c0 = (tid & 3) * 8;
        const size_t a0 = (size_t)(blockIdx.y * 128 + (i0 >> 2)) * 2048 + c0;
        const size_t a1 = (size_t)(blockIdx.y * 128 + (i1 >> 2)) * 2048 + c0;
        const size_t b0 = (size_t)(blockIdx.x * 64 + rB) * 2048 + c0;
        auto stage = [&](int buf, int k0) {
            gload_lds16(A + a0 + k0, &As[buf][i0 * 8]);
            gload_lds16(A + a1 + k0, &As[buf][i1 * 8]);
            stage8_f32((const float*)Wo + b0 + k0, &Bs[buf][rB * LDB + c0]);
        };
        stage(0, 0);
        __syncthreads();
        int cur = 0;
        for (int k0 = 0; k0 < 2048; k0 += 32) {
            if (k0 + 32 < 2048) stage(cur ^ 1, k0 + 32);
            bf16x8 a[2], b[4];
#pragma unroll
            for (int r = 0; r < 2; ++r)
                a[r] = *(const bf16x8*)&As[cur][(wm + r * 16 + r16) * LDA + q8 * 8];
#pragma unroll
            for (int c = 0; c < 4; ++c)
                b[c] = *(const bf16x8*)&Bs[cur][(c * 16 + r16) * LDB + q8 * 8];
#pragma unroll
            for (int r = 0; r < 2; ++r)
#pragma unroll
                for (int c = 0; c < 4; ++c)
                    acc[r][c] = __builtin_amdgcn_mfma_f32_16x16x32_bf16(a[r], b[c], acc[r][c], 0, 0, 0);
            asm volatile("s_waitcnt vmcnt(0) lgkmcnt(0)" ::: "memory");
            __builtin_amdgcn_s_barrier();
            __builtin_amdgcn_sched_barrier(0);
            cur ^= 1;
        }
    }
#pragma unroll
    for (int r = 0; r < 2; ++r)
#pragma unroll
        for (int c = 0; c < 4; ++c)
#pragma unroll
            for (int i = 0; i < 4; ++i) {
                int row = blockIdx.y * 128 + wm + r * 16 + q8 * 4 + i;
                int col = blockIdx.x * 64 + c * 16 + r16;
                C[(size_t)row * 2048 + col] = acc[r][c][i];
            }
}

// ---------------------------------------------------------------------------
// Attention v6 -- FROZEN from R7 (verified: 91.0 us, bank-conflicts 4.19M,
// MfmaUtil 19%). See R7 notes; next attn lever would be VALU/latency, deferred.
// ---------------------------------------------------------------------------
__global__ __launch_bounds__(256, 4) void attn6(
    const bf16* __restrict__ Q, const bf16* __restrict__ LK,
    const bf16* __restrict__ LVt, bf16* __restrict__ O)
{
    __shared__ __align__(16) bf16 Ks[2][64 * 32];   // [s][d], chunk q^((row>>1)&3)
    __shared__ __align__(16) bf16 Vs[2][32 * 64];   // [d][s], chunk q^(row&7)
    __shared__ __align__(16) bf16 Ps[128 * 64];     // 8 regions x 16 rows x 64, XOR-swz

    const int tid  = threadIdx.x;
    const int lane = tid & 63;
    const int w    = tid >> 6;
    const int r16  = lane & 15;
    const int q8   = lane >> 4;
    const int hg = blockIdx.y, h = hg >> 2, g = hg & 3;
    const int t0 = blockIdx.x * 128;

    bf16x8 qb[2];
#pragma unroll
    for (int p = 0; p < 2; ++p)
        qb[p] = *(const bf16x8*)(Q + (size_t)(t0 + w * 32 + p * 16 + r16) * 2048
                                 + h * 128 + g * 32 + q8 * 8);

    const int kr = tid >> 2;
    const int kq = (tid & 3) ^ ((tid >> 3) & 3);
    const bf16* kg = LK + (size_t)kr * 512 + h * 32 + kq * 8;
    const int vd = tid >> 3;
    const int vq = (tid & 7) ^ ((tid >> 3) & 7);
    const bf16* vg = LVt + (size_t)(h * 32 + vd) * 2048 + vq * 8;

    const int ksw = (r16 >> 1) & 3;   // K read swizzle
    const int vsw = r16 & 7;          // V read swizzle

    const int pk7 = r16 & 7;          // row XOR key
    const int ph  = q8 >> 1;          // write gr sub-index
    const int plo = (q8 & 1) * 4;     // write half-gr offset (elems)
    const int pb0 = ((w * 2 + 0) * 16 + r16) * 64;
    const int pb1 = ((w * 2 + 1) * 16 + r16) * 64;

    bf16x8 ones;
#pragma unroll
    for (int j = 0; j < 8; ++j) ones[j] = (bf16)1.0f;

    f32x4 o_acc[2][2] = {};
    f32x4 l_acc[2] = {};
    const f32x4 z = {0.f, 0.f, 0.f, 0.f};

    gload_lds16(kg, &Ks[0][tid * 8]);
    gload_lds16(vg, &Vs[0][tid * 8]);
    __syncthreads();

    int cur = 0;
    for (int sb = 0; sb < 2048; sb += 64) {
        if (sb + 64 < 2048) {
            gload_lds16(kg + (size_t)(sb + 64) * 512, &Ks[cur ^ 1][tid * 8]);
            gload_lds16(vg + (sb + 64),               &Vs[cur ^ 1][tid * 8]);
        }
        const bf16* ks = Ks[cur];
        const bf16* vs = Vs[cur];

        bf16x8 kb[4], vb[2][2];
#pragma unroll
        for (int c = 0; c < 4; ++c)
            kb[c] = *(const bf16x8*)&ks[(c * 16 + r16) * 32 + (q8 ^ ksw) * 8];
#pragma unroll
        for (int kk = 0; kk < 2; ++kk)
#pragma unroll
            for (int ct = 0; ct < 2; ++ct)
                vb[kk][ct] = *(const bf16x8*)&vs[(ct * 16 + r16) * 64
                                                 + (((kk * 4 + q8) ^ vsw) * 8)];

        // ---- phase A: QK^T + exp + P-write for both strips ----
#pragma unroll
        for (int p = 0; p < 2; ++p) {
            const int pbase = p ? pb1 : pb0;
            f32x4 s[4];
            __builtin_amdgcn_s_setprio(1);
#pragma unroll
            for (int c = 0; c < 4; ++c)
                s[c] = __builtin_amdgcn_mfma_f32_16x16x32_bf16(kb[c], qb[p], z, 0, 0, 0);
            __builtin_amdgcn_s_setprio(0);
#pragma unroll
            for (int c = 0; c < 4; ++c) {
                bf16x4 pkv;
#pragma unroll
                for (int i = 0; i < 4; ++i) pkv[i] = (bf16)exp2f(s[c][i]);
                *(bf16x4*)&Ps[pbase + ((c * 2 + ph) ^ pk7) * 8 + plo] = pkv;
            }
        }

        // ---- phase B: PV + row-sum MFMAs for both strips ----
        __builtin_amdgcn_s_setprio(1);
#pragma unroll
        for (int p = 0; p < 2; ++p) {
            const int pbase = p ? pb1 : pb0;
#pragma unroll
            for (int kk = 0; kk < 2; ++kk) {
                bf16x8 ap = *(const bf16x8*)&Ps[pbase + ((kk * 4 + q8) ^ pk7) * 8];
#pragma unroll
                for (int ct = 0; ct < 2; ++ct)
                    o_acc[p][ct] = __builtin_amdgcn_mfma_f32_16x16x32_bf16(ap, vb[kk][ct], o_acc[p][ct], 0, 0, 0);
                l_acc[p] = __builtin_amdgcn_mfma_f32_16x16x32_bf16(ap, ones, l_acc[p], 0, 0, 0);
            }
        }
        __builtin_amdgcn_s_setprio(0);

        asm volatile("s_waitcnt vmcnt(0) lgkmcnt(0)" ::: "memory");
        __builtin_amdgcn_s_barrier();
        __builtin_amdgcn_sched_barrier(0);
        cur ^= 1;
    }

    // epilogue: l_acc[p][i] IS the row-sum for t_local = q8*4+i (no shuffles)
#pragma unroll
    for (int p = 0; p < 2; ++p)
#pragma unroll
        for (int i = 0; i < 4; ++i) {
            float inv = 1.0f / l_acc[p][i];
            int t = t0 + w * 32 + p * 16 + q8 * 4 + i;
#pragma unroll
            for (int ct = 0; ct < 2; ++ct) {
                int d = ct * 16 + r16;
                O[(size_t)t * 2048 + h * 128 + g * 32 + d] = (bf16)(o_acc[p][ct][i] * inv);
            }
        }
}

// ---------------------------------------------------------------------------
// Contract (verified R6 bench): inputs fp32, output fp32.
// ---------------------------------------------------------------------------
extern "C" void kernel_launch(void* const* d_in, const int* in_sizes, int n_in,
                              void* d_out, int out_size, void* d_ws, size_t ws_size,
                              hipStream_t stream) {
    const float* x   = (const float*)d_in[0];
    const float* Wq  = (const float*)d_in[1];
    // d_in[2]=Wk, d_in[3]=Wv: computed-but-unused in the reference -> skipped
    const float* Wlk = (const float*)d_in[4];
    const float* Wlv = (const float*)d_in[5];
    const float* Wo  = (const float*)d_in[6];
    float* out = (float*)d_out;

    const size_t M4 = 4194304, M1 = 1048576;
    const size_t need_fast = (M1 + M1 + M4 + M4 + M1 + M1) * 2;  // 24 MB

    if (ws_size >= need_fast) {
        bf16* xb   = (bf16*)d_out;      // d_out scratch: dead before out_kernel writes
        bf16* Wqb  = xb + M4;
        bf16* p    = (bf16*)d_ws;
        bf16* Wlkb = p; p += M1;
        bf16* Wlvb = p; p += M1;
        bf16* Wob  = p; p += M4;
        bf16* Qp   = p; p += M4;
        bf16* LKp  = p; p += M1;
        bf16* LVt  = p;
        bf16* ATT  = Qp;                // alias: attn block reads its own Q cells first

        cvt5<<<dim3(2048, 5), 256, 0, stream>>>(x, Wq, Wlk, Wlv, Wo,
                                                xb, Wqb, Wlkb, Wlvb, Wob);
        proj_kernel_t<false><<<dim3(48, 16), 256, 0, stream>>>(xb, Wqb, Wlkb, Wlvb,
                                                               Qp, LKp, LVt);
        attn6<<<dim3(16, 64), 256, 0, stream>>>(Qp, LKp, LVt, ATT);
        out_kernel_t<false><<<dim3(32, 16), 256, 0, stream>>>(ATT, Wob, out);
    } else {
        bf16* Qp  = (bf16*)d_ws;
        bf16* LKp = Qp + M4;
        bf16* LVt = LKp + M1;
        bf16* ATT = Qp;

        proj_kernel_t<true><<<dim3(48, 16), 256, 0, stream>>>(x, Wq, Wlk, Wlv,
                                                              Qp, LKp, LVt);
        attn6<<<dim3(16, 64), 256, 0, stream>>>(Qp, LKp, LVt, ATT);
        out_kernel_t<true><<<dim3(32, 16), 256, 0, stream>>>(ATT, Wo, out);
    }
}